// Round 2
// baseline (959.072 us; speedup 1.0000x reference)
//
#include <hip/hip_runtime.h>

#define BQ   2
#define QQ   65536
#define HID  256
#define ENC  64
#define NPIX 4096          // 64*64
#define KCONV 576          // ENC*9

using bf16x8 = __bf16 __attribute__((ext_vector_type(8)));
using f32x4  = float  __attribute__((ext_vector_type(4)));

__device__ __forceinline__ unsigned short f2bf(float f){
  unsigned u = __float_as_uint(f);
  u = (u + 0x7fffu + ((u >> 16) & 1u)) >> 16;
  return (unsigned short)u;
}

// byte offset of bf16 element (row,col) in a [128][256] bf16 LDS tile,
// XOR-swizzled at 16B granularity (kills stride-512B bank conflicts, G4).
__device__ __forceinline__ int xaddr(int row, int col){
  return row*512 + ((((col >> 3) ^ (row & 7)) << 4) | ((col & 7) << 1));
}

// ---------------- prep: weight conversion ---------------------------------
// Wcat k-order is [j*64+cin] (matches direct-from-fpad B-frag gather).
__global__ void prep_kernel(const float* coef_w, const float* freq_w,
                            const float* w0, const float* w1,
                            const float* w2, const float* w3,
                            const float* wo,
                            unsigned short* Wcat, unsigned short* Wmlp,
                            unsigned short* wo_pad){
  int idx = blockIdx.x*256 + threadIdx.x;
  if (idx < 512*KCONV){
    int n = idx / KCONV, k = idx % KCONV;
    int j = k >> 6, cin = k & 63;
    const float* src = (n < 256) ? coef_w : freq_w;
    Wcat[idx] = f2bf(src[(n & 255)*KCONV + cin*9 + j]);
    return;
  }
  int i2 = idx - 512*KCONV;
  if (i2 < 4*65536){
    const float* wl = (i2 < 65536) ? w0 : (i2 < 131072) ? w1
                     : (i2 < 196608) ? w2 : w3;
    Wmlp[i2] = f2bf(wl[i2 & 65535]);
    return;
  }
  int i3 = i2 - 4*65536;
  if (i3 < 16*256){
    int c = i3 >> 8, k = i3 & 255;
    wo_pad[i3] = (c < 3) ? f2bf(wo[c*256 + k]) : (unsigned short)0;
  }
}

// ---------------- enc conv: inp -> fpad bf16 [B][66][66][64] (padded) -----
__global__ __launch_bounds__(256)
void enc_conv_kernel(const float* inp, const float* enc_w, const float* enc_b,
                     unsigned short* fpad){
  __shared__ float wl[ENC*27];
  __shared__ float bl2[ENC];
  __shared__ float tile[256*32];        // 32 KiB, XOR-swizzled [pix][ch32]
  int t = threadIdx.x;
  for (int i = t; i < ENC*27; i += 256) wl[i] = enc_w[i];
  if (t < ENC) bl2[t] = enc_b[t];
  __syncthreads();
  int p  = blockIdx.x*256 + t;
  int b  = p >> 12, yx = p & 4095;
  int y  = yx >> 6, x = yx & 63;
  float v[27];
  #pragma unroll
  for (int c = 0; c < 3; c++)
    #pragma unroll
    for (int dy = 0; dy < 3; dy++)
      #pragma unroll
      for (int dx = 0; dx < 3; dx++){
        int yy = y + dy - 1, xx = x + dx - 1;
        v[c*9 + dy*3 + dx] = (yy >= 0 && yy < 64 && xx >= 0 && xx < 64)
                             ? inp[(b*3 + c)*NPIX + yy*64 + xx] : 0.f;
      }
  int swz_w = (t & 7) << 2;
  for (int h = 0; h < 2; h++){
    // compute 32 channels into swizzled LDS tile
    for (int oc = 0; oc < 8; oc++){
      float4 a4;
      #pragma unroll
      for (int jj = 0; jj < 4; jj++){
        int o = h*32 + oc*4 + jj;
        float acc = bl2[o];
        #pragma unroll
        for (int k = 0; k < 27; k++) acc += wl[o*27 + k]*v[k];
        ((float*)&a4)[jj] = acc;
      }
      *(float4*)(tile + t*32 + ((oc*4) ^ swz_w)) = a4;
    }
    __syncthreads();
    // coalesced bf16 store to padded, pixel-major fpad
    for (int i = 0; i < 8; i++){
      int lin4 = i*256 + t;                 // float4 index in [0,2048)
      int pix  = lin4 >> 3, c4 = (lin4 & 7)*4;
      int chx  = c4 ^ ((pix & 7) << 2);
      float4 vv = *(const float4*)(tile + pix*32 + chx);
      int gp = blockIdx.x*256 + pix;
      int gb = gp >> 12, gy = (gp >> 6) & 63, gx = gp & 63;
      ushort4 us;
      us.x = f2bf(vv.x); us.y = f2bf(vv.y); us.z = f2bf(vv.z); us.w = f2bf(vv.w);
      *(ushort4*)(fpad + ((gb*66 + gy + 1)*66 + gx + 1)*64 + h*32 + c4) = us;
    }
    __syncthreads();
  }
}

// ---------------- conv GEMM: coef/freq (swapped roles, no im2col) ---------
__global__ __launch_bounds__(256)
void conv_gemm_kernel(const unsigned short* fpad, const unsigned short* Wcat,
                      const float* coef_b, const float* freq_b,
                      float* coefT, float* freqT){
  int wave = threadIdx.x >> 6, lane = threadIdx.x & 63;
  int l16 = lane & 15, g = lane >> 4;
  int tile = blockIdx.x*4 + wave;           // 16384 = 512 pt * 32 nt
  int nt = tile & 31, pt = tile >> 5;
  int gp = pt*16 + l16;                     // pixel handled by this lane (B col)
  int b = gp >> 12, y = (gp >> 6) & 63, x = gp & 63;
  const unsigned short* fbase = fpad + ((b*66 + y)*66 + x)*64;
  const unsigned short* Wp = Wcat + (nt*16 + l16)*KCONV + g*8;
  f32x4 acc;
  {
    const float* bsrc = (nt < 16) ? coef_b : freq_b;
    float4 b4 = *(const float4*)(bsrc + ((nt*16) & 255) + g*4);
    acc[0] = b4.x; acc[1] = b4.y; acc[2] = b4.z; acc[3] = b4.w;
  }
  #pragma unroll
  for (int kk = 0; kk < 18; kk++){
    int j = kk >> 1, dy = j/3, dx = j%3;
    bf16x8 bfrag = *(const bf16x8*)(fbase + (dy*66 + dx)*64 + (kk & 1)*32 + g*8);
    bf16x8 afrag = *(const bf16x8*)(Wp + kk*32);
    acc = __builtin_amdgcn_mfma_f32_16x16x32_bf16(afrag, bfrag, acc, 0, 0, 0);
  }
  // D: row(n) = g*4+reg, col(pix) = l16 -> float4 store, coalesced 16B
  float4 o4; o4.x = acc[0]; o4.y = acc[1]; o4.z = acc[2]; o4.w = acc[3];
  if (nt < 16) *(float4*)(coefT + gp*256 + nt*16 + g*4)         = o4;
  else         *(float4*)(freqT + gp*256 + (nt - 16)*16 + g*4)  = o4;
}

// ---------------- fused gather/fourier + 4-layer MLP + out layer ----------
__global__ __launch_bounds__(512, 4)
void mlp_kernel(const float* coefT, const float* freqT,
                const float* coord, const float* cell, const float* phase_w,
                const unsigned short* Wmlp,
                const float* b0, const float* b1, const float* b2, const float* b3,
                const unsigned short* wo_pad, const float* bo,
                float* areas, float* pred){
  __shared__ __align__(16) char Xs[128*256*2];   // 64 KiB swizzled bf16 [128][256]
  int t = threadIdx.x;
  int r0 = blockIdx.x*128;
  int wave = t >> 6, lane = t & 63;
  int l16 = lane & 15, g = lane >> 4;

  // ---- build X (gather + fourier), one wave per row, coalesced ----
  for (int rr = 0; rr < 16; rr++){
    int lr = wave*16 + rr;
    int gr = r0 + lr;
    int s  = gr & 3, bq = gr >> 2;
    float c0 = coord[bq*2], c1 = coord[bq*2+1];
    float ce0 = cell[bq*2]*64.f, ce1 = cell[bq*2+1]*64.f;
    float vx = (s & 2) ? 1.f : -1.f;
    float vy = (s & 1) ? 1.f : -1.f;
    const float RX = 1.f/64.f;
    float cy = fminf(fmaxf(c0 + vx*RX + 1e-6f, -1.f + 1e-6f), 1.f - 1e-6f);
    float cx = fminf(fmaxf(c1 + vy*RX + 1e-6f, -1.f + 1e-6f), 1.f - 1e-6f);
    int iy = min(max((int)rintf((cy + 1.f)*32.f - 0.5f), 0), 63);
    int ix = min(max((int)rintf((cx + 1.f)*32.f - 0.5f), 0), 63);
    float qy = -1.f + (2*iy + 1)*(1.f/64.f);
    float qx = -1.f + (2*ix + 1)*(1.f/64.f);
    float rel0 = (c0 - qy)*64.f, rel1 = (c1 - qx)*64.f;
    if (lane == 0) areas[gr] = fabsf(rel0*rel1) + 1e-9f;
    int b = bq >> 16;
    int pix = b*NPIX + iy*64 + ix;
    const float* cR = coefT + pix*256;
    const float* fR = freqT + pix*256;
    #pragma unroll
    for (int hh = 0; hh < 2; hh++){
      int p = hh*64 + lane;                       // pair index 0..127
      float2 fv = *(const float2*)(fR + 2*p);
      float2 pw = *(const float2*)(phase_w + 2*p);
      float qf = fv.x*rel0 + fv.y*rel1 + ce0*pw.x + ce1*pw.y;
      float cv = cospif(qf), sv = sinpif(qf);
      float xlo = cR[p]       * cv;
      float xhi = cR[128 + p] * sv;
      *(unsigned short*)(Xs + xaddr(lr, p))       = f2bf(xlo);
      *(unsigned short*)(Xs + xaddr(lr, 128 + p)) = f2bf(xhi);
    }
  }
  __syncthreads();

  const float* const bls[4] = {b0, b1, b2, b3};
  int wr = wave >> 2;                 // 0..1 row-group
  int wn = wave & 3;                  // 0..3 neuron-group
  int rbase = wr*64, nbase = wn*64;   // wave tile: 64 rows x 64 neurons

  #pragma unroll
  for (int l = 0; l < 4; l++){
    const unsigned short* Wl = Wmlp + l*65536;
    f32x4 acc[4][4];
    #pragma unroll
    for (int nt = 0; nt < 4; nt++){
      float4 bv = *(const float4*)(bls[l] + nbase + nt*16 + g*4);
      #pragma unroll
      for (int rt = 0; rt < 4; rt++){
        acc[rt][nt][0] = bv.x; acc[rt][nt][1] = bv.y;
        acc[rt][nt][2] = bv.z; acc[rt][nt][3] = bv.w;
      }
    }
    #pragma unroll
    for (int kk = 0; kk < 8; kk++){
      bf16x8 xf[4];
      #pragma unroll
      for (int rt = 0; rt < 4; rt++)
        xf[rt] = *(const bf16x8*)(Xs + xaddr(rbase + rt*16 + l16, kk*32 + g*8));
      #pragma unroll
      for (int nt = 0; nt < 4; nt++){
        bf16x8 wf = *(const bf16x8*)(Wl + (nbase + nt*16 + l16)*256 + kk*32 + g*8);
        #pragma unroll
        for (int rt = 0; rt < 4; rt++)
          acc[rt][nt] = __builtin_amdgcn_mfma_f32_16x16x32_bf16(wf, xf[rt],
                                                                acc[rt][nt], 0,0,0);
      }
    }
    __syncthreads();   // all reads of Xs done -> safe to overwrite
    // D: row(n)=g*4+reg, col(r)=l16 -> each lane writes 4 consecutive cols
    #pragma unroll
    for (int rt = 0; rt < 4; rt++)
      #pragma unroll
      for (int nt = 0; nt < 4; nt++){
        int row = rbase + rt*16 + l16;
        int col = nbase + nt*16 + g*4;
        unsigned lo = (unsigned)f2bf(fmaxf(acc[rt][nt][0], 0.f))
                    | ((unsigned)f2bf(fmaxf(acc[rt][nt][1], 0.f)) << 16);
        unsigned hi = (unsigned)f2bf(fmaxf(acc[rt][nt][2], 0.f))
                    | ((unsigned)f2bf(fmaxf(acc[rt][nt][3], 0.f)) << 16);
        uint2 u; u.x = lo; u.y = hi;
        *(uint2*)(Xs + xaddr(row, col)) = u;
      }
    __syncthreads();
  }

  // ---- output layer: A = wo_pad (16 padded rows), wave w -> 16 rows ----
  {
    f32x4 acc = {0.f, 0.f, 0.f, 0.f};
    #pragma unroll
    for (int kk = 0; kk < 8; kk++){
      bf16x8 wf = *(const bf16x8*)(wo_pad + l16*256 + kk*32 + g*8);
      bf16x8 xf = *(const bf16x8*)(Xs + xaddr(wave*16 + l16, kk*32 + g*8));
      acc = __builtin_amdgcn_mfma_f32_16x16x32_bf16(wf, xf, acc, 0, 0, 0);
    }
    if (g == 0){                         // n = reg (0..3), row = l16
      int row = r0 + wave*16 + l16;
      pred[row*3 + 0] = acc[0] + bo[0];
      pred[row*3 + 1] = acc[1] + bo[1];
      pred[row*3 + 2] = acc[2] + bo[2];
    }
  }
}

// ---------------- combine: area blend + bilinear residual + BN sums -------
__global__ void combine_kernel(const float* pred, const float* areas,
                               const float* coord, const float* inp,
                               float* retbuf, float* bnsums){
  int bq = blockIdx.x*256 + threadIdx.x;   // 0..131071
  int b  = bq >> 16;
  float4 ar = *(const float4*)(areas + bq*4);
  float tot = ar.x + ar.y + ar.z + ar.w;
  float w0_ = ar.w/tot, w1_ = ar.z/tot, w2_ = ar.y/tot, w3_ = ar.x/tot;
  const float* pp = pred + bq*12;
  float r_[3];
  #pragma unroll
  for (int c = 0; c < 3; c++)
    r_[c] = pp[c]*w0_ + pp[3+c]*w1_ + pp[6+c]*w2_ + pp[9+c]*w3_;

  float c0 = coord[bq*2], c1 = coord[bq*2+1];
  float fy = (c0 + 1.f)*32.f - 0.5f, fx = (c1 + 1.f)*32.f - 0.5f;
  float y0f = floorf(fy), x0f = floorf(fx);
  float wy = fy - y0f, wx = fx - x0f;
  int y0 = min(max((int)y0f, 0), 63), y1 = min(max((int)y0f + 1, 0), 63);
  int x0 = min(max((int)x0f, 0), 63), x1 = min(max((int)x0f + 1, 0), 63);
  const float* ib = inp + b*3*NPIX;
  #pragma unroll
  for (int c = 0; c < 3; c++){
    const float* pl = ib + c*NPIX;
    float v00 = pl[y0*64 + x0], v01 = pl[y0*64 + x1];
    float v10 = pl[y1*64 + x0], v11 = pl[y1*64 + x1];
    r_[c] += v00*(1.f-wy)*(1.f-wx) + v01*(1.f-wy)*wx
           + v10*wy*(1.f-wx)       + v11*wy*wx;
    retbuf[bq*3 + c] = r_[c];
  }
  #pragma unroll
  for (int c = 0; c < 3; c++){
    float s = r_[c], ss = r_[c]*r_[c];
    #pragma unroll
    for (int off = 32; off; off >>= 1){
      s  += __shfl_down(s,  off);
      ss += __shfl_down(ss, off);
    }
    if ((threadIdx.x & 63) == 0){
      atomicAdd(&bnsums[c],     s);
      atomicAdd(&bnsums[4 + c], ss);
    }
  }
}

// ---------------- batchnorm normalize -------------------------------------
__global__ void normalize_kernel(const float* retbuf, const float* bnsums,
                                 const float* gamma, const float* beta,
                                 float* out){
  int idx = blockIdx.x*256 + threadIdx.x;
  if (idx >= BQ*QQ*3) return;
  int c = idx % 3;
  const float n = (float)(BQ*QQ);
  float mean = bnsums[c] / n;
  float var  = bnsums[4 + c] / n - mean*mean;
  out[idx] = (retbuf[idx] - mean) * rsqrtf(var + 1e-5f) * gamma[c] + beta[c];
}

extern "C" void kernel_launch(void* const* d_in, const int* in_sizes, int n_in,
                              void* d_out, int out_size, void* d_ws, size_t ws_size,
                              hipStream_t stream){
  const float* inp    = (const float*)d_in[0];
  const float* coord  = (const float*)d_in[1];
  const float* cell   = (const float*)d_in[2];
  const float* enc_w  = (const float*)d_in[3];
  const float* enc_b  = (const float*)d_in[4];
  const float* coef_w = (const float*)d_in[5];
  const float* coef_b = (const float*)d_in[6];
  const float* freq_w = (const float*)d_in[7];
  const float* freq_b = (const float*)d_in[8];
  const float* phase_w= (const float*)d_in[9];
  const float* w0 = (const float*)d_in[10]; const float* b0 = (const float*)d_in[11];
  const float* w1 = (const float*)d_in[12]; const float* b1 = (const float*)d_in[13];
  const float* w2 = (const float*)d_in[14]; const float* b2 = (const float*)d_in[15];
  const float* w3 = (const float*)d_in[16]; const float* b3 = (const float*)d_in[17];
  const float* wo = (const float*)d_in[18]; const float* bo = (const float*)d_in[19];
  const float* gamma = (const float*)d_in[20]; const float* beta = (const float*)d_in[21];

  char* ws = (char*)d_ws;
  unsigned short* fpad   = (unsigned short*)(ws + 0);          // 1,115,136 B
  float*          coefT  = (float*)(ws + 1116160);             // 8 MB
  float*          freqT  = (float*)(ws + 9504768);             // 8 MB
  unsigned short* Wcat   = (unsigned short*)(ws + 17893376);   // 576 KB
  unsigned short* Wmlp   = (unsigned short*)(ws + 18483200);   // 512 KB
  unsigned short* wo_pad = (unsigned short*)(ws + 19007488);   // 8 KB
  float*          areas  = (float*)(ws + 19015680);            // 2 MB
  float*          pred   = (float*)(ws + 21112832);            // 6 MB
  float*          retbuf = (float*)(ws + 27404288);            // 1.5 MB
  float*          bnsums = (float*)(ws + 28977152);            // 32 B
  if (ws_size < 28977184) return;

  hipMemsetAsync(fpad, 0, 1115136, stream);       // zero border (bf16 0 = 0.0)
  hipMemsetAsync(bnsums, 0, 32, stream);
  prep_kernel<<<2192, 256, 0, stream>>>(coef_w, freq_w, w0, w1, w2, w3, wo,
                                        Wcat, Wmlp, wo_pad);
  enc_conv_kernel<<<32, 256, 0, stream>>>(inp, enc_w, enc_b, fpad);
  conv_gemm_kernel<<<4096, 256, 0, stream>>>(fpad, Wcat, coef_b, freq_b,
                                             coefT, freqT);
  mlp_kernel<<<4096, 512, 0, stream>>>(coefT, freqT, coord, cell, phase_w, Wmlp,
                                       b0, b1, b2, b3, wo_pad, bo, areas, pred);
  combine_kernel<<<512, 256, 0, stream>>>(pred, areas, coord, inp, retbuf, bnsums);
  normalize_kernel<<<1536, 256, 0, stream>>>(retbuf, bnsums, gamma, beta,
                                             (float*)d_out);
}